// Round 2
// baseline (562.462 us; speedup 1.0000x reference)
//
#include <hip/hip_runtime.h>

typedef unsigned short ushort_t;
typedef __attribute__((ext_vector_type(8))) short short8;
typedef __attribute__((ext_vector_type(4))) float float4_t;

// ---------- fast math helpers ----------
__device__ __forceinline__ float frcp(float x) { return __builtin_amdgcn_rcpf(x); }
__device__ __forceinline__ float fsig(float x) { return frcp(1.f + __expf(-x)); }
__device__ __forceinline__ float ftanh(float x) { return 1.f - 2.f * frcp(1.f + __expf(2.f * x)); }

__device__ __forceinline__ ushort_t f2bf(float f) {
    union { float f; unsigned u; } v; v.f = f;
    unsigned u = v.u;
    unsigned r = (u + 0x7fffu + ((u >> 16) & 1u)) >> 16;
    return (ushort_t)r;
}
__device__ __forceinline__ float bf2f(ushort_t s) {
    union { unsigned u; float f; } v; v.u = ((unsigned)s) << 16;
    return v.f;
}

// ---------------------------------------------------------------------------
// Block 0 MD-LSTM: C=2, Cin=1, H=64, W=256. One wave per (dir,b).
// Lane i = row i. h_l = own prev reg, h_u = shfl_up(1). No LDS, no barriers.
// ---------------------------------------------------------------------------
__global__ __launch_bounds__(64) void k_mdlstm0(
    const float* __restrict__ x, const float* __restrict__ Wx,
    const float* __restrict__ Wh, const float* __restrict__ Wv,
    const float* __restrict__ bias, float* __restrict__ h0)
{
    const int dir = blockIdx.x >> 4, b = blockIdx.x & 15;
    const int lane = threadIdx.x;
    const bool fH = dir >= 2, fW = (dir & 1) != 0;
    const int ri = fH ? 63 - lane : lane;

    float wx[10], bs[10], wh[2][10], wv[2][10];
#pragma unroll
    for (int n = 0; n < 10; n++) { wx[n] = Wx[dir * 10 + n]; bs[n] = bias[dir * 10 + n]; }
#pragma unroll
    for (int k = 0; k < 2; k++)
#pragma unroll
        for (int n = 0; n < 10; n++) {
            wh[k][n] = Wh[(dir * 2 + k) * 10 + n];
            wv[k][n] = Wv[(dir * 2 + k) * 10 + n];
        }

    const float* xrow = x + (b * 64 + ri) * 256;          // Cin = 1
    float* orow = h0 + (((dir * 16 + b) * 64 + ri) * 256) * 2;

    float h0r = 0.f, h1r = 0.f, c0r = 0.f, c1r = 0.f;

    auto ld = [&](int d) -> float {
        int j = d - lane; j = j < 0 ? 0 : (j > 255 ? 255 : j);
        int cj = fW ? 255 - j : j;
        return xrow[cj];
    };
    float xp0 = ld(0), xp1 = ld(1);

    for (int d = 0; d < 319; d++) {
        float xv = xp0;
        xp0 = xp1;
        xp1 = ld(d + 2);                                  // prefetch depth 2

        float hu0 = __shfl_up(h0r, 1), hu1 = __shfl_up(h1r, 1);
        float cu0 = __shfl_up(c0r, 1), cu1 = __shfl_up(c1r, 1);
        if (lane == 0) { hu0 = 0.f; hu1 = 0.f; cu0 = 0.f; cu1 = 0.f; }

        int j = d - lane;
        if (j >= 0 && j < 256) {
            float a[10];
#pragma unroll
            for (int n = 0; n < 10; n++) {
                float t = fmaf(xv, wx[n], bs[n]);
                t = fmaf(h0r, wh[0][n], t); t = fmaf(h1r, wh[1][n], t);
                t = fmaf(hu0, wv[0][n], t); t = fmaf(hu1, wv[1][n], t);
                a[n] = t;
            }
            // layout: i=a[0:2] f1=a[2:4] f2=a[4:6] o=a[6:8] g=a[8:10]
            float cn0 = fsig(a[0]) * ftanh(a[8]) + fsig(a[2]) * c0r + fsig(a[4]) * cu0;
            float cn1 = fsig(a[1]) * ftanh(a[9]) + fsig(a[3]) * c1r + fsig(a[5]) * cu1;
            float hn0 = fsig(a[6]) * ftanh(cn0);
            float hn1 = fsig(a[7]) * ftanh(cn1);
            h0r = hn0; h1r = hn1; c0r = cn0; c1r = cn1;
            int cj = fW ? 255 - j : j;
            float2 hv; hv.x = hn0; hv.y = hn1;
            *(float2*)&orow[cj * 2] = hv;
        }
    }
}

// ---------------------------------------------------------------------------
// conv0: h0 (sum 4 dirs) [B,2,64,256] -> conv(6,2,2,4) s2 + tanh -> x1[32][127][16][6]
// ---------------------------------------------------------------------------
__global__ __launch_bounds__(128) void k_conv0(
    const float* __restrict__ h0, const float* __restrict__ cw,
    const float* __restrict__ cb, float* __restrict__ x1)
{
    int blk = blockIdx.x;                // 32*127
    int oh = blk / 127, ow = blk % 127;
    int t = threadIdx.x;
    if (t >= 96) return;
    int b = t / 6, co = t % 6;
    float w[2][2][4];
#pragma unroll
    for (int ci = 0; ci < 2; ci++)
#pragma unroll
        for (int kh = 0; kh < 2; kh++)
#pragma unroll
            for (int kw = 0; kw < 4; kw++)
                w[ci][kh][kw] = cw[((co * 2 + ci) * 2 + kh) * 4 + kw];
    float acc = cb[co];
    for (int dirb = 0; dirb < 4; dirb++) {
#pragma unroll
        for (int kh = 0; kh < 2; kh++) {
#pragma unroll
            for (int kw = 0; kw < 4; kw++) {
                const float* ptr = h0 + ((((dirb * 16 + b) * 64) + (2 * oh + kh)) * 256 + (2 * ow + kw)) * 2;
                float2 hv = *(const float2*)ptr;
                acc = fmaf(hv.x, w[0][kh][kw], acc);
                acc = fmaf(hv.y, w[1][kh][kw], acc);
            }
        }
    }
    x1[((oh * 127 + ow) * 16 + b) * 6 + co] = ftanh(acc);
}

// ---------------------------------------------------------------------------
// Block 1 MD-LSTM: C=10, Cin=6, H=32, W=127. Block per (dir,b), 320 thr =
// (cell,unit). LDS double-buffered h/c (extra zero row kills the i==0 branch).
// ---------------------------------------------------------------------------
__global__ __launch_bounds__(320, 1) void k_mdlstm1(
    const float* __restrict__ x1, const float* __restrict__ Wx,
    const float* __restrict__ Wh, const float* __restrict__ Wv,
    const float* __restrict__ bias, float* __restrict__ h1)
{
    const int dir = blockIdx.x >> 4, b = blockIdx.x & 15;
    const bool fH = dir >= 2, fW = (dir & 1) != 0;
    const int tid = threadIdx.x;
    const int cell = tid / 10, u = tid % 10;      // cell < 32
    const int ri = fH ? 31 - cell : cell;

    __shared__ float hb[2][33][12];               // row 0 = permanent zeros
    __shared__ float cb[2][33][12];
    for (int i = tid; i < 2 * 33 * 12; i += 320) { ((float*)hb)[i] = 0.f; ((float*)cb)[i] = 0.f; }
    __syncthreads();

    float wxr[6][5], whr[10][5], wvr[10][5], br[5];
#pragma unroll
    for (int g = 0; g < 5; g++) {
        int n = g * 10 + u;
        br[g] = bias[dir * 50 + n];
#pragma unroll
        for (int ci = 0; ci < 6; ci++) wxr[ci][g] = Wx[(dir * 6 + ci) * 50 + n];
#pragma unroll
        for (int k = 0; k < 10; k++) {
            whr[k][g] = Wh[(dir * 10 + k) * 50 + n];
            wvr[k][g] = Wv[(dir * 10 + k) * 50 + n];
        }
    }

    float creg = 0.f;
    float xr[6], xn[6];
    auto xload = [&](int d, float* dst) {
        int j = d - cell; j = j < 0 ? 0 : (j > 126 ? 126 : j);
        int cj = fW ? 126 - j : j;
        const float* p2 = x1 + ((ri * 127 + cj) * 16 + b) * 6;
#pragma unroll
        for (int k2 = 0; k2 < 6; k2++) dst[k2] = p2[k2];
    };
    xload(0, xr); xload(1, xn);

    int p = 0;
    for (int d = 0; d < 158; d++) {
        int j = d - cell;
        bool act = (j >= 0) && (j < 127);
        float hl[10], hu[10];
#pragma unroll
        for (int k = 0; k < 10; k++) { hl[k] = hb[p][cell + 1][k]; hu[k] = hb[p][cell][k]; }
        float cu = cb[p][cell][u];
        if (act) {
            float a[5];
#pragma unroll
            for (int g = 0; g < 5; g++) {
                float t = br[g];
#pragma unroll
                for (int ci = 0; ci < 6; ci++) t = fmaf(xr[ci], wxr[ci][g], t);
#pragma unroll
                for (int k = 0; k < 10; k++) t = fmaf(hl[k], whr[k][g], t);
#pragma unroll
                for (int k = 0; k < 10; k++) t = fmaf(hu[k], wvr[k][g], t);
                a[g] = t;
            }
            float cn = fsig(a[0]) * ftanh(a[4]) + fsig(a[1]) * creg + fsig(a[2]) * cu;
            float hn = fsig(a[3]) * ftanh(cn);
            creg = cn;
            hb[1 - p][cell + 1][u] = hn;
            cb[1 - p][cell + 1][u] = cn;
            int cj = fW ? 126 - j : j;
            h1[(((dir * 16 + b) * 32 + ri) * 127 + cj) * 10 + u] = hn;
        }
#pragma unroll
        for (int k2 = 0; k2 < 6; k2++) xr[k2] = xn[k2];
        xload(d + 2, xn);
        __syncthreads();
        p ^= 1;
    }
}

// ---------------------------------------------------------------------------
// conv1: h1 (sum 4 dirs) [B,10,32,127] -> conv(20,10,2,4) s2 + tanh -> x2[16][62][16][20]
// ---------------------------------------------------------------------------
__global__ __launch_bounds__(320, 1) void k_conv1(
    const float* __restrict__ h1, const float* __restrict__ cw,
    const float* __restrict__ cb, float* __restrict__ x2)
{
    int blk = blockIdx.x;                 // 16*62
    int oh = blk / 62, ow = blk % 62;
    int t = threadIdx.x;
    int b = t / 20, co = t % 20;
    float w[10][2][4];
#pragma unroll
    for (int ci = 0; ci < 10; ci++)
#pragma unroll
        for (int kh = 0; kh < 2; kh++)
#pragma unroll
            for (int kw = 0; kw < 4; kw++)
                w[ci][kh][kw] = cw[((co * 10 + ci) * 2 + kh) * 4 + kw];
    float acc = cb[co];
    for (int dirb = 0; dirb < 4; dirb++) {
#pragma unroll
        for (int kh = 0; kh < 2; kh++) {
#pragma unroll
            for (int kw = 0; kw < 4; kw++) {
                const float* ptr = h1 + ((((dirb * 16 + b) * 32) + (2 * oh + kh)) * 127 + (2 * ow + kw)) * 10;
#pragma unroll
                for (int ci = 0; ci < 10; ci++)
                    acc = fmaf(ptr[ci], w[ci][kh][kw], acc);
            }
        }
    }
    x2[((oh * 62 + ow) * 16 + b) * 20 + co] = ftanh(acc);
}

// ---------------------------------------------------------------------------
// prep B for block2 MFMA, SPLIT hi/lo bf16 (double-bf16 precision):
// Bh/Bl[dir][k<128][n<256] = [Wh(50); Wv(50); Wx(20); 0pad]
// ---------------------------------------------------------------------------
__global__ __launch_bounds__(256) void k_prepB2(
    const float* __restrict__ Wh, const float* __restrict__ Wv,
    const float* __restrict__ Wx, ushort_t* __restrict__ Bh,
    ushort_t* __restrict__ Bl)
{
    int idx = blockIdx.x * 256 + threadIdx.x;      // 4*128*256 = 131072
    if (idx >= 131072) return;
    int dir = idx >> 15; int k = (idx >> 8) & 127; int n = idx & 255;
    float v = 0.f;
    if (n < 250) {
        if (k < 50)       v = Wh[(dir * 50 + k) * 250 + n];
        else if (k < 100) v = Wv[(dir * 50 + (k - 50)) * 250 + n];
        else if (k < 120) v = Wx[(dir * 20 + (k - 100)) * 250 + n];
    }
    ushort_t hi = f2bf(v);
    Bh[idx] = hi;
    Bl[idx] = f2bf(v - bf2f(hi));
}

// ---------------------------------------------------------------------------
// Block 2 MD-LSTM: C=50, Cin=20, H=16, W=62. Block per (dir,b), 1024 thr.
// MFMA 16x16x32 bf16, A and B both split hi/lo:
//   P = Ah*Bh + Al*Bh + Ah*Bl   (12 MFMAs/wave/step, ~2^-17 rel error)
// Wave w owns n-tile w (N=256). A rows padded to 17 dwords (no bank conflicts).
// ---------------------------------------------------------------------------
__global__ __launch_bounds__(1024, 1) void k_mdlstm2(
    const float* __restrict__ x2, const ushort_t* __restrict__ BmH,
    const ushort_t* __restrict__ BmL,
    const float* __restrict__ bias, float* __restrict__ h2)
{
    const int dir = blockIdx.x >> 4, b = blockIdx.x & 15;
    const bool fH = dir >= 2, fW = (dir & 1) != 0;
    const int tid = threadIdx.x;
    const int wave = tid >> 6, lane = tid & 63;

    __shared__ __align__(16) ushort_t Ah[2][16][136];
    __shared__ __align__(16) ushort_t Al[2][16][136];
    __shared__ float P[16][260];
    __shared__ float cbuf[2][16][52];

    for (int i = tid; i < 2 * 16 * 136; i += 1024) { ((ushort_t*)Ah)[i] = 0; ((ushort_t*)Al)[i] = 0; }
    __syncthreads();
    if (tid < 20) {                                   // x-part of A for step 0 (cell 0 only)
        int ci = tid;
        int rr = fH ? 15 : 0, cc = fW ? 61 : 0;
        float xv = x2[((rr * 62 + cc) * 16 + b) * 20 + ci];
        ushort_t xh = f2bf(xv);
        Ah[0][0][100 + ci] = xh;
        Al[0][0][100 + ci] = f2bf(xv - bf2f(xh));
    }

    short8 bfragH[4], bfragL[4];
    {
        const int n = wave * 16 + (lane & 15);
#pragma unroll
        for (int q = 0; q < 4; q++) {
#pragma unroll
            for (int jj = 0; jj < 8; jj++) {
                int k = q * 32 + (lane >> 4) * 8 + jj;
                bfragH[q][jj] = (short)BmH[(dir * 128 + k) * 256 + n];
                bfragL[q][jj] = (short)BmL[(dir * 128 + k) * 256 + n];
            }
        }
    }

    const int cell = tid / 50, u = tid % 50;          // gate-phase mapping (tid<800)
    float bi = 0, bf1 = 0, bf2v = 0, bo = 0, bg = 0;
    if (tid < 800) {
        bi   = bias[dir * 250 + u];
        bf1  = bias[dir * 250 + 50 + u];
        bf2v = bias[dir * 250 + 100 + u];
        bo   = bias[dir * 250 + 150 + u];
        bg   = bias[dir * 250 + 200 + u];
    }
    const int rr_c = fH ? 15 - cell : cell;
    float creg = 0.f;
    __syncthreads();

    int p = 0;
    for (int d = 0; d < 77; d++) {
        // ---- MFMA phase: preacts P[16][250] = A * B (split hi/lo) ----
        float4_t acc = {0.f, 0.f, 0.f, 0.f};
        const int arow = lane & 15;
        const int koff = (lane >> 4) * 8;
#pragma unroll
        for (int q = 0; q < 4; q++) {
            short8 af = *(const short8*)&Ah[p][arow][q * 32 + koff];
            acc = __builtin_amdgcn_mfma_f32_16x16x32_bf16(af, bfragL[q], acc, 0, 0, 0);
        }
#pragma unroll
        for (int q = 0; q < 4; q++) {
            short8 af = *(const short8*)&Al[p][arow][q * 32 + koff];
            acc = __builtin_amdgcn_mfma_f32_16x16x32_bf16(af, bfragH[q], acc, 0, 0, 0);
        }
#pragma unroll
        for (int q = 0; q < 4; q++) {
            short8 af = *(const short8*)&Ah[p][arow][q * 32 + koff];
            acc = __builtin_amdgcn_mfma_f32_16x16x32_bf16(af, bfragH[q], acc, 0, 0, 0);
        }
        {
            int col = wave * 16 + (lane & 15);
            int r0 = (lane >> 4) * 4;
#pragma unroll
            for (int r = 0; r < 4; r++) P[r0 + r][col] = acc[r];
        }
        __syncthreads();

        // ---- gate phase ----
        if (tid < 800) {
            int j = d - cell;
            if (j >= 0 && j < 62) {
                float ai  = P[cell][u] + bi;
                float af1 = P[cell][50 + u] + bf1;
                float af2 = P[cell][100 + u] + bf2v;
                float ao  = P[cell][150 + u] + bo;
                float ag  = P[cell][200 + u] + bg;
                float cu = (cell == 0) ? 0.f : cbuf[p][cell - 1][u];
                float cn = fsig(ai) * ftanh(ag) + fsig(af1) * creg + fsig(af2) * cu;
                float hn = fsig(ao) * ftanh(cn);
                creg = cn;
                cbuf[1 - p][cell][u] = cn;
                ushort_t hh = f2bf(hn);
                float hhf = bf2f(hh);
                ushort_t hlo = f2bf(hn - hhf);
                Ah[1 - p][cell][u] = hh;
                Al[1 - p][cell][u] = hlo;
                if (cell < 15) { Ah[1 - p][cell + 1][50 + u] = hh; Al[1 - p][cell + 1][50 + u] = hlo; }
                int cc = fW ? 61 - j : j;
                h2[(((dir * 16 + b) * 16 + rr_c) * 62 + cc) * 50 + u] = hn;
            }
        }
        // ---- x-part of A for step d+1 ----
        if (tid < 320) {
            int xc = tid / 20, ci = tid % 20;
            int jn = d + 1 - xc;
            if (jn >= 0 && jn < 62) {
                int rr = fH ? 15 - xc : xc, cc = fW ? 61 - jn : jn;
                float xv = x2[((rr * 62 + cc) * 16 + b) * 20 + ci];
                ushort_t xh = f2bf(xv);
                Ah[1 - p][xc][100 + ci] = xh;
                Al[1 - p][xc][100 + ci] = f2bf(xv - bf2f(xh));
            }
        }
        __syncthreads();
        p ^= 1;
    }
}

// ---------------------------------------------------------------------------
// final: out[b][r][c][n] = sum_{dir,cc} h2[dir][b][r][c][cc]*dW[dir][cc][n] + sum_dir db[dir][n]
// ---------------------------------------------------------------------------
__global__ __launch_bounds__(256) void k_final(
    const float* __restrict__ h2, const float* __restrict__ dW,
    const float* __restrict__ db, float* __restrict__ out)
{
    int blk = blockIdx.x;                  // 16*62
    int r = blk / 62, c = blk % 62;
    int t = threadIdx.x;
    __shared__ float hb[3200];             // [4][16][50]
    for (int i = t; i < 3200; i += 256) {
        int dirb = i / 800, rem = i % 800, b = rem / 50, u = rem % 50;
        hb[i] = h2[(((dirb * 16 + b) * 16 + r) * 62 + c) * 50 + u];
    }
    __syncthreads();
    for (int o = t; o < 1600; o += 256) {
        int b = o / 100, n = o % 100;
        float acc = db[n] + db[100 + n] + db[200 + n] + db[300 + n];
#pragma unroll
        for (int dirb = 0; dirb < 4; dirb++) {
            const float* hp = hb + (dirb * 16 + b) * 50;
            const float* wp = dW + dirb * 5000 + n;
#pragma unroll 10
            for (int cc2 = 0; cc2 < 50; cc2++)
                acc = fmaf(hp[cc2], wp[cc2 * 100], acc);
        }
        out[((b * 16 + r) * 62 + c) * 100 + n] = acc;
    }
}

// ---------------------------------------------------------------------------
extern "C" void kernel_launch(void* const* d_in, const int* in_sizes, int n_in,
                              void* d_out, int out_size, void* d_ws, size_t ws_size,
                              hipStream_t stream)
{
    const float* x     = (const float*)d_in[0];
    const float* p0_Wx = (const float*)d_in[1];
    const float* p0_Wh = (const float*)d_in[2];
    const float* p0_Wv = (const float*)d_in[3];
    const float* p0_b  = (const float*)d_in[4];
    const float* c0_w  = (const float*)d_in[5];
    const float* c0_b  = (const float*)d_in[6];
    const float* p1_Wx = (const float*)d_in[7];
    const float* p1_Wh = (const float*)d_in[8];
    const float* p1_Wv = (const float*)d_in[9];
    const float* p1_b  = (const float*)d_in[10];
    const float* c1_w  = (const float*)d_in[11];
    const float* c1_b  = (const float*)d_in[12];
    const float* p2_Wx = (const float*)d_in[13];
    const float* p2_Wh = (const float*)d_in[14];
    const float* p2_Wv = (const float*)d_in[15];
    const float* p2_b  = (const float*)d_in[16];
    const float* dW    = (const float*)d_in[17];
    const float* db    = (const float*)d_in[18];
    float* out = (float*)d_out;
    float* ws  = (float*)d_ws;

    float* h0 = ws;                        // 4*16*64*256*2  = 2,097,152 fl
    float* x1 = h0 + 2097152;              // 32*127*16*6    =   390,144 fl
    float* h1 = x1 + 390144;               // 4*16*32*127*10 = 2,600,960 fl
    float* x2 = h1 + 2600960;              // 16*62*16*20    =   317,440 fl
    float* h2 = x2 + 317440;               // 4*16*16*62*50  = 3,174,400 fl
    ushort_t* BmH = (ushort_t*)(h2 + 3174400); // 4*128*256 bf16
    ushort_t* BmL = BmH + 131072;              // 4*128*256 bf16

    k_prepB2<<<512, 256, 0, stream>>>(p2_Wh, p2_Wv, p2_Wx, BmH, BmL);
    k_mdlstm0<<<64, 64, 0, stream>>>(x, p0_Wx, p0_Wh, p0_Wv, p0_b, h0);
    k_conv0<<<32 * 127, 128, 0, stream>>>(h0, c0_w, c0_b, x1);
    k_mdlstm1<<<64, 320, 0, stream>>>(x1, p1_Wx, p1_Wh, p1_Wv, p1_b, h1);
    k_conv1<<<16 * 62, 320, 0, stream>>>(h1, c1_w, c1_b, x2);
    k_mdlstm2<<<64, 1024, 0, stream>>>(x2, BmH, BmL, p2_b, h2);
    k_final<<<16 * 62, 256, 0, stream>>>(h2, dW, db, out);
}

// Round 3
// 551.357 us; speedup vs baseline: 1.0201x; 1.0201x over previous
//
#include <hip/hip_runtime.h>

typedef unsigned short ushort_t;
typedef __attribute__((ext_vector_type(8))) short short8;
typedef __attribute__((ext_vector_type(4))) float float4_t;
typedef __attribute__((ext_vector_type(2))) float v2f;

// ---------- fast math helpers ----------
__device__ __forceinline__ float frcp(float x) { return __builtin_amdgcn_rcpf(x); }
__device__ __forceinline__ float fsig(float x) { return frcp(1.f + __expf(-x)); }
__device__ __forceinline__ float ftanh(float x) { return 1.f - 2.f * frcp(1.f + __expf(2.f * x)); }
// exp2-domain variants (argument pre-scaled by -log2e for sigmoid, +2log2e for tanh)
__device__ __forceinline__ float sig_e2(float a) { return frcp(1.f + __builtin_amdgcn_exp2f(a)); }
__device__ __forceinline__ float th_e2(float a) { return 1.f - 2.f * frcp(1.f + __builtin_amdgcn_exp2f(a)); }

__device__ __forceinline__ ushort_t f2bf(float f) {
    union { float f; unsigned u; } v; v.f = f;
    unsigned u = v.u;
    unsigned r = (u + 0x7fffu + ((u >> 16) & 1u)) >> 16;
    return (ushort_t)r;
}
__device__ __forceinline__ float bf2f(ushort_t s) {
    union { unsigned u; float f; } v; v.u = ((unsigned)s) << 16;
    return v.f;
}
// whole-wave shift-right-by-1 via DPP (lane0 gets 0). 1 VALU op vs ds_bpermute.
__device__ __forceinline__ float dpp_shr1(float x) {
    int i = __builtin_bit_cast(int, x);
    int r = __builtin_amdgcn_update_dpp(0, i, 0x138 /*wave_shr:1*/, 0xf, 0xf, true);
    return __builtin_bit_cast(float, r);
}

// ---------------------------------------------------------------------------
// Block 0 MD-LSTM: C=2, Cin=1, H=64, W=256. One wave per (dir,b).
// Lane i = row i. h_l = own prev reg, h_u = DPP wave_shr1. Weights pre-scaled
// into exp2 domain; gate math packed as v2f (v_pk_fma_f32).
// ---------------------------------------------------------------------------
__global__ __launch_bounds__(64) void k_mdlstm0(
    const float* __restrict__ x, const float* __restrict__ Wx,
    const float* __restrict__ Wh, const float* __restrict__ Wv,
    const float* __restrict__ bias, float* __restrict__ h0)
{
    const int dir = blockIdx.x >> 4, b = blockIdx.x & 15;
    const int lane = threadIdx.x;
    const bool fH = dir >= 2, fW = (dir & 1) != 0;
    const int ri = fH ? 63 - lane : lane;
    const float L2E = 1.44269504088896340736f;

    // gate g in {0:i,1:f1,2:f2,3:o,4:g}; pair = units (0,1); n = g*2+un
    v2f wx[5], bs[5], wh0[5], wh1[5], wv0[5], wv1[5];
#pragma unroll
    for (int g = 0; g < 5; g++) {
        float sc = (g == 4) ? 2.f * L2E : -L2E;
#pragma unroll
        for (int un = 0; un < 2; un++) {
            int n = g * 2 + un;
            wx[g][un]  = Wx[dir * 10 + n] * sc;
            bs[g][un]  = bias[dir * 10 + n] * sc;
            wh0[g][un] = Wh[(dir * 2 + 0) * 10 + n] * sc;
            wh1[g][un] = Wh[(dir * 2 + 1) * 10 + n] * sc;
            wv0[g][un] = Wv[(dir * 2 + 0) * 10 + n] * sc;
            wv1[g][un] = Wv[(dir * 2 + 1) * 10 + n] * sc;
        }
    }

    const float* xrow = x + (b * 64 + ri) * 256;          // Cin = 1
    float* orow = h0 + (((dir * 16 + b) * 64 + ri) * 256) * 2;

    v2f hr = {0.f, 0.f}, cr = {0.f, 0.f};

    auto ld = [&](int d) -> float {
        int j = d - lane; j = j < 0 ? 0 : (j > 255 ? 255 : j);
        int cj = fW ? 255 - j : j;
        return xrow[cj];
    };
    float xp0 = ld(0), xp1 = ld(1);

    for (int d = 0; d < 319; d++) {
        float xv = xp0;
        xp0 = xp1;
        xp1 = ld(d + 2);                                  // prefetch depth 2

        float hu0 = dpp_shr1(hr.x), hu1 = dpp_shr1(hr.y);
        float cu0 = dpp_shr1(cr.x), cu1 = dpp_shr1(cr.y);

        int j = d - lane;
        if (j >= 0 && j < 256) {
            v2f a[5];
#pragma unroll
            for (int g = 0; g < 5; g++) {
                v2f t = __builtin_elementwise_fma((v2f){xv, xv}, wx[g], bs[g]);
                t = __builtin_elementwise_fma((v2f){hr.x, hr.x}, wh0[g], t);
                t = __builtin_elementwise_fma((v2f){hr.y, hr.y}, wh1[g], t);
                t = __builtin_elementwise_fma((v2f){hu0, hu0}, wv0[g], t);
                t = __builtin_elementwise_fma((v2f){hu1, hu1}, wv1[g], t);
                a[g] = t;
            }
            v2f si  = {sig_e2(a[0].x), sig_e2(a[0].y)};
            v2f sf1 = {sig_e2(a[1].x), sig_e2(a[1].y)};
            v2f sf2 = {sig_e2(a[2].x), sig_e2(a[2].y)};
            v2f so  = {sig_e2(a[3].x), sig_e2(a[3].y)};
            v2f tg  = {th_e2(a[4].x),  th_e2(a[4].y)};
            v2f cu  = {cu0, cu1};
            v2f cn = si * tg + sf1 * cr + sf2 * cu;
            v2f tc = {th_e2(cn.x * (2.f * L2E)), th_e2(cn.y * (2.f * L2E))};
            hr = so * tc;
            cr = cn;
            int cj = fW ? 255 - j : j;
            float2 hv; hv.x = hr.x; hv.y = hr.y;
            *(float2*)&orow[cj * 2] = hv;
        } else {
            // keep inactive lanes' state at 0 so shifted-in neighbors are 0
            hr = (v2f){0.f, 0.f};
            cr = (v2f){0.f, 0.f};
        }
    }
}

// ---------------------------------------------------------------------------
// conv0: h0 (sum 4 dirs) [B,2,64,256] -> conv(6,2,2,4) s2 + tanh -> x1[32][127][16][6]
// ---------------------------------------------------------------------------
__global__ __launch_bounds__(128) void k_conv0(
    const float* __restrict__ h0, const float* __restrict__ cw,
    const float* __restrict__ cb, float* __restrict__ x1)
{
    int blk = blockIdx.x;                // 32*127
    int oh = blk / 127, ow = blk % 127;
    int t = threadIdx.x;
    if (t >= 96) return;
    int b = t / 6, co = t % 6;
    float w[2][2][4];
#pragma unroll
    for (int ci = 0; ci < 2; ci++)
#pragma unroll
        for (int kh = 0; kh < 2; kh++)
#pragma unroll
            for (int kw = 0; kw < 4; kw++)
                w[ci][kh][kw] = cw[((co * 2 + ci) * 2 + kh) * 4 + kw];
    float acc = cb[co];
    for (int dirb = 0; dirb < 4; dirb++) {
#pragma unroll
        for (int kh = 0; kh < 2; kh++) {
#pragma unroll
            for (int kw = 0; kw < 4; kw++) {
                const float* ptr = h0 + ((((dirb * 16 + b) * 64) + (2 * oh + kh)) * 256 + (2 * ow + kw)) * 2;
                float2 hv = *(const float2*)ptr;
                acc = fmaf(hv.x, w[0][kh][kw], acc);
                acc = fmaf(hv.y, w[1][kh][kw], acc);
            }
        }
    }
    x1[((oh * 127 + ow) * 16 + b) * 6 + co] = ftanh(acc);
}

// ---------------------------------------------------------------------------
// Block 1 MD-LSTM via MFMA: C=10, Cin=6, H=32, W=127. Block per (dir,b),
// 1024 thr. A[32 cells][K=32: hl(10)|hu(10)|x(6)|pad6] bf16 hi/lo, dbuf.
// B[K=32][N=64: 5 gates x 10 units, pad] in regs (hi/lo). 8 MFMA waves
// (2 m-tiles x 4 n-tiles), 3 mfma each (AhBh+AlBh+AhBl). Gate phase on
// tid<320 = (cell,u); x-staging on waves 8-10 (overlaps MFMA phase).
// ---------------------------------------------------------------------------
__global__ __launch_bounds__(1024, 1) void k_mdlstm1(
    const float* __restrict__ x1, const float* __restrict__ Wx,
    const float* __restrict__ Wh, const float* __restrict__ Wv,
    const float* __restrict__ bias, float* __restrict__ h1)
{
    const int dir = blockIdx.x >> 4, b = blockIdx.x & 15;
    const bool fH = dir >= 2, fW = (dir & 1) != 0;
    const int tid = threadIdx.x;
    const int wave = tid >> 6, lane = tid & 63;

    __shared__ __align__(16) ushort_t Ah[2][32][40];
    __shared__ __align__(16) ushort_t Al[2][32][40];
    __shared__ float P[32][68];
    __shared__ float cbuf[2][33][12];     // row 0 = permanent zeros

    for (int i = tid; i < 2 * 32 * 40; i += 1024) { ((ushort_t*)Ah)[i] = 0; ((ushort_t*)Al)[i] = 0; }
    for (int i = tid; i < 2 * 33 * 12; i += 1024) ((float*)cbuf)[i] = 0.f;
    __syncthreads();
    if (tid < 6) {                        // x for step 0 (cell 0 only)
        int rr = fH ? 31 : 0, cc = fW ? 126 : 0;
        float xv = x1[((rr * 127 + cc) * 16 + b) * 6 + tid];
        ushort_t xh = f2bf(xv);
        Ah[0][0][20 + tid] = xh;
        Al[0][0][20 + tid] = f2bf(xv - bf2f(xh));
    }

    // B fragments in regs: wave w -> mt = w&1 (rows), nt = w>>1 (gate cols)
    const int mt = wave & 1, nt = wave >> 1;
    short8 bh = {0,0,0,0,0,0,0,0}, bl = {0,0,0,0,0,0,0,0};
    if (wave < 8) {
        int n = nt * 16 + (lane & 15);
#pragma unroll
        for (int jj = 0; jj < 8; jj++) {
            int k = (lane >> 4) * 8 + jj;
            float v = 0.f;
            if (n < 50) {
                if (k < 10)      v = Wh[(dir * 10 + k) * 50 + n];
                else if (k < 20) v = Wv[(dir * 10 + (k - 10)) * 50 + n];
                else if (k < 26) v = Wx[(dir * 6 + (k - 20)) * 50 + n];
            }
            ushort_t hi = f2bf(v);
            bh[jj] = (short)hi;
            bl[jj] = (short)f2bf(v - bf2f(hi));
        }
    }

    const int cell = tid / 10, u = tid % 10;      // gate mapping (tid<320)
    float br[5];
#pragma unroll
    for (int g = 0; g < 5; g++) br[g] = (tid < 320) ? bias[dir * 50 + g * 10 + u] : 0.f;
    const int ri = fH ? 31 - cell : cell;
    float creg = 0.f;
    __syncthreads();

    int p = 0;
    for (int d = 0; d < 158; d++) {
        // ---- MFMA phase (waves 0-7) ----
        if (wave < 8) {
            const int arow = mt * 16 + (lane & 15);
            const int koff = (lane >> 4) * 8;
            short8 ah = *(const short8*)&Ah[p][arow][koff];
            short8 al = *(const short8*)&Al[p][arow][koff];
            float4_t acc = {0.f, 0.f, 0.f, 0.f};
            acc = __builtin_amdgcn_mfma_f32_16x16x32_bf16(ah, bh, acc, 0, 0, 0);
            acc = __builtin_amdgcn_mfma_f32_16x16x32_bf16(al, bh, acc, 0, 0, 0);
            acc = __builtin_amdgcn_mfma_f32_16x16x32_bf16(ah, bl, acc, 0, 0, 0);
            int col = nt * 16 + (lane & 15);
            int r0 = (lane >> 4) * 4;
#pragma unroll
            for (int r = 0; r < 4; r++) P[mt * 16 + r0 + r][col] = acc[r];
        } else if (tid >= 512 && tid < 704) {
            // ---- x-staging for step d+1 (overlaps MFMA; writes buffer 1-p) ----
            int s = tid - 512, xc = s / 6, ci = s % 6;
            int jn = d + 1 - xc;
            if (jn >= 0 && jn < 127) {
                int rr = fH ? 31 - xc : xc, cc = fW ? 126 - jn : jn;
                float xv = x1[((rr * 127 + cc) * 16 + b) * 6 + ci];
                ushort_t xh = f2bf(xv);
                Ah[1 - p][xc][20 + ci] = xh;
                Al[1 - p][xc][20 + ci] = f2bf(xv - bf2f(xh));
            }
        }
        __syncthreads();

        // ---- gate phase (tid<320) ----
        if (tid < 320) {
            int j = d - cell;
            if (j >= 0 && j < 127) {
                float ai  = P[cell][u]      + br[0];
                float af1 = P[cell][10 + u] + br[1];
                float af2 = P[cell][20 + u] + br[2];
                float ao  = P[cell][30 + u] + br[3];
                float ag  = P[cell][40 + u] + br[4];
                float cu = cbuf[p][cell][u];
                float cn = fsig(ai) * ftanh(ag) + fsig(af1) * creg + fsig(af2) * cu;
                float hn = fsig(ao) * ftanh(cn);
                creg = cn;
                cbuf[1 - p][cell + 1][u] = cn;
                ushort_t hh = f2bf(hn);
                float hhf = bf2f(hh);
                ushort_t hlo = f2bf(hn - hhf);
                Ah[1 - p][cell][u] = hh;          // hl slot for next step
                Al[1 - p][cell][u] = hlo;
                if (cell < 31) { Ah[1 - p][cell + 1][10 + u] = hh; Al[1 - p][cell + 1][10 + u] = hlo; }
                int cj = fW ? 126 - j : j;
                h1[(((dir * 16 + b) * 32 + ri) * 127 + cj) * 10 + u] = hn;
            }
        }
        __syncthreads();
        p ^= 1;
    }
}

// ---------------------------------------------------------------------------
// conv1: h1 (sum 4 dirs) [B,10,32,127] -> conv(20,10,2,4) s2 + tanh -> x2[16][62][16][20]
// ---------------------------------------------------------------------------
__global__ __launch_bounds__(320, 1) void k_conv1(
    const float* __restrict__ h1, const float* __restrict__ cw,
    const float* __restrict__ cb, float* __restrict__ x2)
{
    int blk = blockIdx.x;                 // 16*62
    int oh = blk / 62, ow = blk % 62;
    int t = threadIdx.x;
    int b = t / 20, co = t % 20;
    float w[10][2][4];
#pragma unroll
    for (int ci = 0; ci < 10; ci++)
#pragma unroll
        for (int kh = 0; kh < 2; kh++)
#pragma unroll
            for (int kw = 0; kw < 4; kw++)
                w[ci][kh][kw] = cw[((co * 10 + ci) * 2 + kh) * 4 + kw];
    float acc = cb[co];
    for (int dirb = 0; dirb < 4; dirb++) {
#pragma unroll
        for (int kh = 0; kh < 2; kh++) {
#pragma unroll
            for (int kw = 0; kw < 4; kw++) {
                const float* ptr = h1 + ((((dirb * 16 + b) * 32) + (2 * oh + kh)) * 127 + (2 * ow + kw)) * 10;
#pragma unroll
                for (int ci = 0; ci < 10; ci++)
                    acc = fmaf(ptr[ci], w[ci][kh][kw], acc);
            }
        }
    }
    x2[((oh * 62 + ow) * 16 + b) * 20 + co] = ftanh(acc);
}

// ---------------------------------------------------------------------------
// prep B for block2 MFMA, SPLIT hi/lo bf16:
// Bh/Bl[dir][k<128][n<256] = [Wh(50); Wv(50); Wx(20); 0pad]
// ---------------------------------------------------------------------------
__global__ __launch_bounds__(256) void k_prepB2(
    const float* __restrict__ Wh, const float* __restrict__ Wv,
    const float* __restrict__ Wx, ushort_t* __restrict__ Bh,
    ushort_t* __restrict__ Bl)
{
    int idx = blockIdx.x * 256 + threadIdx.x;      // 4*128*256 = 131072
    if (idx >= 131072) return;
    int dir = idx >> 15; int k = (idx >> 8) & 127; int n = idx & 255;
    float v = 0.f;
    if (n < 250) {
        if (k < 50)       v = Wh[(dir * 50 + k) * 250 + n];
        else if (k < 100) v = Wv[(dir * 50 + (k - 50)) * 250 + n];
        else if (k < 120) v = Wx[(dir * 20 + (k - 100)) * 250 + n];
    }
    ushort_t hi = f2bf(v);
    Bh[idx] = hi;
    Bl[idx] = f2bf(v - bf2f(hi));
}

// ---------------------------------------------------------------------------
// Block 2 MD-LSTM: C=50, Cin=20, H=16, W=62. Block per (dir,b), 1024 thr.
// MFMA 16x16x32 bf16, A and B hi/lo: P = AhBh + AlBh + AhBl (12 mfma/wave).
// x-staging moved to waves 13-15 (off the gate threads).
// ---------------------------------------------------------------------------
__global__ __launch_bounds__(1024, 1) void k_mdlstm2(
    const float* __restrict__ x2, const ushort_t* __restrict__ BmH,
    const ushort_t* __restrict__ BmL,
    const float* __restrict__ bias, float* __restrict__ h2)
{
    const int dir = blockIdx.x >> 4, b = blockIdx.x & 15;
    const bool fH = dir >= 2, fW = (dir & 1) != 0;
    const int tid = threadIdx.x;
    const int wave = tid >> 6, lane = tid & 63;

    __shared__ __align__(16) ushort_t Ah[2][16][136];
    __shared__ __align__(16) ushort_t Al[2][16][136];
    __shared__ float P[16][260];
    __shared__ float cbuf[2][16][52];

    for (int i = tid; i < 2 * 16 * 136; i += 1024) { ((ushort_t*)Ah)[i] = 0; ((ushort_t*)Al)[i] = 0; }
    __syncthreads();
    if (tid < 20) {                                   // x for step 0 (cell 0 only)
        int ci = tid;
        int rr = fH ? 15 : 0, cc = fW ? 61 : 0;
        float xv = x2[((rr * 62 + cc) * 16 + b) * 20 + ci];
        ushort_t xh = f2bf(xv);
        Ah[0][0][100 + ci] = xh;
        Al[0][0][100 + ci] = f2bf(xv - bf2f(xh));
    }

    short8 bfragH[4], bfragL[4];
    {
        const int n = wave * 16 + (lane & 15);
#pragma unroll
        for (int q = 0; q < 4; q++) {
#pragma unroll
            for (int jj = 0; jj < 8; jj++) {
                int k = q * 32 + (lane >> 4) * 8 + jj;
                bfragH[q][jj] = (short)BmH[(dir * 128 + k) * 256 + n];
                bfragL[q][jj] = (short)BmL[(dir * 128 + k) * 256 + n];
            }
        }
    }

    const int cell = tid / 50, u = tid % 50;          // gate mapping (tid<800)
    float bi = 0, bf1 = 0, bf2v = 0, bo = 0, bg = 0;
    if (tid < 800) {
        bi   = bias[dir * 250 + u];
        bf1  = bias[dir * 250 + 50 + u];
        bf2v = bias[dir * 250 + 100 + u];
        bo   = bias[dir * 250 + 150 + u];
        bg   = bias[dir * 250 + 200 + u];
    }
    const int rr_c = fH ? 15 - cell : cell;
    float creg = 0.f;
    __syncthreads();

    int p = 0;
    for (int d = 0; d < 77; d++) {
        // ---- MFMA phase ----
        {
            const int arow = lane & 15;
            const int koff = (lane >> 4) * 8;
            short8 ah[4], al[4];
#pragma unroll
            for (int q = 0; q < 4; q++) {
                ah[q] = *(const short8*)&Ah[p][arow][q * 32 + koff];
                al[q] = *(const short8*)&Al[p][arow][q * 32 + koff];
            }
            float4_t acc = {0.f, 0.f, 0.f, 0.f};
#pragma unroll
            for (int q = 0; q < 4; q++) acc = __builtin_amdgcn_mfma_f32_16x16x32_bf16(ah[q], bfragH[q], acc, 0, 0, 0);
#pragma unroll
            for (int q = 0; q < 4; q++) acc = __builtin_amdgcn_mfma_f32_16x16x32_bf16(al[q], bfragH[q], acc, 0, 0, 0);
#pragma unroll
            for (int q = 0; q < 4; q++) acc = __builtin_amdgcn_mfma_f32_16x16x32_bf16(ah[q], bfragL[q], acc, 0, 0, 0);
            int col = wave * 16 + (lane & 15);
            int r0 = (lane >> 4) * 4;
#pragma unroll
            for (int r = 0; r < 4; r++) P[r0 + r][col] = acc[r];
        }
        __syncthreads();

        // ---- gate phase (tid<800) ----
        if (tid < 800) {
            int j = d - cell;
            if (j >= 0 && j < 62) {
                float ai  = P[cell][u] + bi;
                float af1 = P[cell][50 + u] + bf1;
                float af2 = P[cell][100 + u] + bf2v;
                float ao  = P[cell][150 + u] + bo;
                float ag  = P[cell][200 + u] + bg;
                float cu = (cell == 0) ? 0.f : cbuf[p][cell - 1][u];
                float cn = fsig(ai) * ftanh(ag) + fsig(af1) * creg + fsig(af2) * cu;
                float hn = fsig(ao) * ftanh(cn);
                creg = cn;
                cbuf[1 - p][cell][u] = cn;
                ushort_t hh = f2bf(hn);
                float hhf = bf2f(hh);
                ushort_t hlo = f2bf(hn - hhf);
                Ah[1 - p][cell][u] = hh;
                Al[1 - p][cell][u] = hlo;
                if (cell < 15) { Ah[1 - p][cell + 1][50 + u] = hh; Al[1 - p][cell + 1][50 + u] = hlo; }
                int cc = fW ? 61 - j : j;
                h2[(((dir * 16 + b) * 16 + rr_c) * 62 + cc) * 50 + u] = hn;
            }
        } else if (tid >= 832 && tid < 992) {
            // ---- x-staging for step d+1 on otherwise-idle waves ----
            int s = tid - 832;
#pragma unroll
            for (int it = 0; it < 2; it++) {
                int item = s + it * 160;
                int xc = item / 20, ci = item % 20;
                int jn = d + 1 - xc;
                if (jn >= 0 && jn < 62) {
                    int rr = fH ? 15 - xc : xc, cc = fW ? 61 - jn : jn;
                    float xv = x2[((rr * 62 + cc) * 16 + b) * 20 + ci];
                    ushort_t xh = f2bf(xv);
                    Ah[1 - p][xc][100 + ci] = xh;
                    Al[1 - p][xc][100 + ci] = f2bf(xv - bf2f(xh));
                }
            }
        }
        __syncthreads();
        p ^= 1;
    }
}

// ---------------------------------------------------------------------------
// final: out[b][r][c][n] = sum_{dir,cc} h2[dir][b][r][c][cc]*dW[dir][cc][n] + sum_dir db[dir][n]
// ---------------------------------------------------------------------------
__global__ __launch_bounds__(256) void k_final(
    const float* __restrict__ h2, const float* __restrict__ dW,
    const float* __restrict__ db, float* __restrict__ out)
{
    int blk = blockIdx.x;                  // 16*62
    int r = blk / 62, c = blk % 62;
    int t = threadIdx.x;
    __shared__ float hb[3200];             // [4][16][50]
    for (int i = t; i < 3200; i += 256) {
        int dirb = i / 800, rem = i % 800, b = rem / 50, u = rem % 50;
        hb[i] = h2[(((dirb * 16 + b) * 16 + r) * 62 + c) * 50 + u];
    }
    __syncthreads();
    for (int o = t; o < 1600; o += 256) {
        int b = o / 100, n = o % 100;
        float acc = db[n] + db[100 + n] + db[200 + n] + db[300 + n];
#pragma unroll
        for (int dirb = 0; dirb < 4; dirb++) {
            const float* hp = hb + (dirb * 16 + b) * 50;
            const float* wp = dW + dirb * 5000 + n;
#pragma unroll 10
            for (int cc2 = 0; cc2 < 50; cc2++)
                acc = fmaf(hp[cc2], wp[cc2 * 100], acc);
        }
        out[((b * 16 + r) * 62 + c) * 100 + n] = acc;
    }
}

// ---------------------------------------------------------------------------
extern "C" void kernel_launch(void* const* d_in, const int* in_sizes, int n_in,
                              void* d_out, int out_size, void* d_ws, size_t ws_size,
                              hipStream_t stream)
{
    const float* x     = (const float*)d_in[0];
    const float* p0_Wx = (const float*)d_in[1];
    const float* p0_Wh = (const float*)d_in[2];
    const float* p0_Wv = (const float*)d_in[3];
    const float* p0_b  = (const float*)d_in[4];
    const float* c0_w  = (const float*)d_in[5];
    const float* c0_b  = (const float*)d_in[6];
    const float* p1_Wx = (const float*)d_in[7];
    const float* p1_Wh = (const float*)d_in[8];
    const float* p1_Wv = (const float*)d_in[9];
    const float* p1_b  = (const float*)d_in[10];
    const float* c1_w  = (const float*)d_in[11];
    const float* c1_b  = (const float*)d_in[12];
    const float* p2_Wx = (const float*)d_in[13];
    const float* p2_Wh = (const float*)d_in[14];
    const float* p2_Wv = (const float*)d_in[15];
    const float* p2_b  = (const float*)d_in[16];
    const float* dW    = (const float*)d_in[17];
    const float* db    = (const float*)d_in[18];
    float* out = (float*)d_out;
    float* ws  = (float*)d_ws;

    float* h0 = ws;                        // 4*16*64*256*2  = 2,097,152 fl
    float* x1 = h0 + 2097152;              // 32*127*16*6    =   390,144 fl
    float* h1 = x1 + 390144;               // 4*16*32*127*10 = 2,600,960 fl
    float* x2 = h1 + 2600960;              // 16*62*16*20    =   317,440 fl
    float* h2 = x2 + 317440;               // 4*16*16*62*50  = 3,174,400 fl
    ushort_t* BmH = (ushort_t*)(h2 + 3174400); // 4*128*256 bf16
    ushort_t* BmL = BmH + 131072;              // 4*128*256 bf16

    k_prepB2<<<512, 256, 0, stream>>>(p2_Wh, p2_Wv, p2_Wx, BmH, BmL);
    k_mdlstm0<<<64, 64, 0, stream>>>(x, p0_Wx, p0_Wh, p0_Wv, p0_b, h0);
    k_conv0<<<32 * 127, 128, 0, stream>>>(h0, c0_w, c0_b, x1);
    k_mdlstm1<<<64, 1024, 0, stream>>>(x1, p1_Wx, p1_Wh, p1_Wv, p1_b, h1);
    k_conv1<<<16 * 62, 320, 0, stream>>>(h1, c1_w, c1_b, x2);
    k_mdlstm2<<<64, 1024, 0, stream>>>(x2, BmH, BmL, p2_b, h2);
    k_final<<<16 * 62, 256, 0, stream>>>(h2, dW, db, out);
}

// Round 4
// 477.252 us; speedup vs baseline: 1.1785x; 1.1553x over previous
//
#include <hip/hip_runtime.h>

typedef unsigned short ushort_t;
typedef __attribute__((ext_vector_type(8))) short short8;
typedef __attribute__((ext_vector_type(4))) float float4_t;
typedef __attribute__((ext_vector_type(2))) float v2f;

// ---------- fast math helpers ----------
__device__ __forceinline__ float frcp(float x) { return __builtin_amdgcn_rcpf(x); }
__device__ __forceinline__ float fsig(float x) { return frcp(1.f + __expf(-x)); }
__device__ __forceinline__ float ftanh(float x) { return 1.f - 2.f * frcp(1.f + __expf(2.f * x)); }
// exp2-domain variants (argument pre-scaled by -log2e for sigmoid, +2log2e for tanh)
__device__ __forceinline__ float sig_e2(float a) { return frcp(1.f + __builtin_amdgcn_exp2f(a)); }
__device__ __forceinline__ float th_e2(float a) { return 1.f - 2.f * frcp(1.f + __builtin_amdgcn_exp2f(a)); }

__device__ __forceinline__ ushort_t f2bf(float f) {
    union { float f; unsigned u; } v; v.f = f;
    unsigned u = v.u;
    unsigned r = (u + 0x7fffu + ((u >> 16) & 1u)) >> 16;
    return (ushort_t)r;
}
__device__ __forceinline__ float bf2f(ushort_t s) {
    union { unsigned u; float f; } v; v.u = ((unsigned)s) << 16;
    return v.f;
}
// whole-wave shift-right-by-1 via DPP (lane0 gets 0). 1 VALU op vs ds_bpermute.
__device__ __forceinline__ float dpp_shr1(float x) {
    int i = __builtin_bit_cast(int, x);
    int r = __builtin_amdgcn_update_dpp(0, i, 0x138 /*wave_shr:1*/, 0xf, 0xf, true);
    return __builtin_bit_cast(float, r);
}

// ---------------------------------------------------------------------------
// Block 0 MD-LSTM: C=2, Cin=1, H=64, W=256. One wave per (dir,b).
// x row-set staged to LDS once (64KB); loop is LDS+VALU only, h-stores
// fire-and-forget. Lane i = row i; h_u via DPP wave_shr1.
// ---------------------------------------------------------------------------
__global__ __launch_bounds__(64) void k_mdlstm0(
    const float* __restrict__ x, const float* __restrict__ Wx,
    const float* __restrict__ Wh, const float* __restrict__ Wv,
    const float* __restrict__ bias, float* __restrict__ h0)
{
    const int dir = blockIdx.x >> 4, b = blockIdx.x & 15;
    const int lane = threadIdx.x;
    const bool fH = dir >= 2, fW = (dir & 1) != 0;
    const int ri = fH ? 63 - lane : lane;
    const float L2E = 1.44269504088896340736f;

    __shared__ float Xs[64 * 256];                        // 64 KB, exact
    {
        const float* xg = x + b * 64 * 256;
        // 4096 float4s; lane-consecutive -> coalesced 16B; LDS write b128
        for (int i4 = lane; i4 < 4096; i4 += 64) {
            int row = i4 >> 6, c4 = (i4 & 63) << 2;
            float4 v = *(const float4*)(xg + (row << 8) + c4);
            *(float4*)&Xs[(row << 8) + c4] = v;
        }
    }
    __syncthreads();

    // gate g in {0:i,1:f1,2:f2,3:o,4:g}; pair = units (0,1)
    v2f wx[5], bs[5], wh0[5], wh1[5], wv0[5], wv1[5];
#pragma unroll
    for (int g = 0; g < 5; g++) {
        float sc = (g == 4) ? 2.f * L2E : -L2E;
#pragma unroll
        for (int un = 0; un < 2; un++) {
            int n = g * 2 + un;
            wx[g][un]  = Wx[dir * 10 + n] * sc;
            bs[g][un]  = bias[dir * 10 + n] * sc;
            wh0[g][un] = Wh[(dir * 2 + 0) * 10 + n] * sc;
            wh1[g][un] = Wh[(dir * 2 + 1) * 10 + n] * sc;
            wv0[g][un] = Wv[(dir * 2 + 0) * 10 + n] * sc;
            wv1[g][un] = Wv[(dir * 2 + 1) * 10 + n] * sc;
        }
    }

    float* orow = h0 + (((dir * 16 + b) * 64 + ri) * 256) * 2;
    v2f hr = {0.f, 0.f}, cr = {0.f, 0.f};

    auto ld = [&](int d) -> float {                       // LDS read
        int j = d - lane; j = j < 0 ? 0 : (j > 255 ? 255 : j);
        int cj = fW ? 255 - j : j;
        return Xs[(ri << 8) + cj];
    };
    float xp0 = ld(0), xp1 = ld(1);

    for (int d = 0; d < 319; d++) {
        float xv = xp0;
        xp0 = xp1;
        xp1 = ld(d + 2);                                  // prefetch depth 2

        float hu0 = dpp_shr1(hr.x), hu1 = dpp_shr1(hr.y);
        float cu0 = dpp_shr1(cr.x), cu1 = dpp_shr1(cr.y);

        int j = d - lane;
        if (j >= 0 && j < 256) {
            v2f a[5];
#pragma unroll
            for (int g = 0; g < 5; g++) {
                v2f t = __builtin_elementwise_fma((v2f){xv, xv}, wx[g], bs[g]);
                t = __builtin_elementwise_fma((v2f){hr.x, hr.x}, wh0[g], t);
                t = __builtin_elementwise_fma((v2f){hr.y, hr.y}, wh1[g], t);
                t = __builtin_elementwise_fma((v2f){hu0, hu0}, wv0[g], t);
                t = __builtin_elementwise_fma((v2f){hu1, hu1}, wv1[g], t);
                a[g] = t;
            }
            v2f si  = {sig_e2(a[0].x), sig_e2(a[0].y)};
            v2f sf1 = {sig_e2(a[1].x), sig_e2(a[1].y)};
            v2f sf2 = {sig_e2(a[2].x), sig_e2(a[2].y)};
            v2f so  = {sig_e2(a[3].x), sig_e2(a[3].y)};
            v2f tg  = {th_e2(a[4].x),  th_e2(a[4].y)};
            v2f cu  = {cu0, cu1};
            v2f cn = si * tg + sf1 * cr + sf2 * cu;
            v2f tc = {th_e2(cn.x * (2.f * L2E)), th_e2(cn.y * (2.f * L2E))};
            hr = so * tc;
            cr = cn;
            int cj = fW ? 255 - j : j;
            float2 hv; hv.x = hr.x; hv.y = hr.y;
            *(float2*)&orow[cj * 2] = hv;                 // fire-and-forget
        } else {
            hr = (v2f){0.f, 0.f};                         // keep inactive state 0
            cr = (v2f){0.f, 0.f};
        }
    }
}

// ---------------------------------------------------------------------------
// conv0: h0 (sum 4 dirs) [B,2,64,256] -> conv(6,2,2,4) s2 + tanh -> x1[32][127][16][6]
// ---------------------------------------------------------------------------
__global__ __launch_bounds__(128) void k_conv0(
    const float* __restrict__ h0, const float* __restrict__ cw,
    const float* __restrict__ cb, float* __restrict__ x1)
{
    int blk = blockIdx.x;                // 32*127
    int oh = blk / 127, ow = blk % 127;
    int t = threadIdx.x;
    if (t >= 96) return;
    int b = t / 6, co = t % 6;
    float w[2][2][4];
#pragma unroll
    for (int ci = 0; ci < 2; ci++)
#pragma unroll
        for (int kh = 0; kh < 2; kh++)
#pragma unroll
            for (int kw = 0; kw < 4; kw++)
                w[ci][kh][kw] = cw[((co * 2 + ci) * 2 + kh) * 4 + kw];
    float acc = cb[co];
    for (int dirb = 0; dirb < 4; dirb++) {
#pragma unroll
        for (int kh = 0; kh < 2; kh++) {
#pragma unroll
            for (int kw = 0; kw < 4; kw++) {
                const float* ptr = h0 + ((((dirb * 16 + b) * 64) + (2 * oh + kh)) * 256 + (2 * ow + kw)) * 2;
                float2 hv = *(const float2*)ptr;
                acc = fmaf(hv.x, w[0][kh][kw], acc);
                acc = fmaf(hv.y, w[1][kh][kw], acc);
            }
        }
    }
    x1[((oh * 127 + ow) * 16 + b) * 6 + co] = ftanh(acc);
}

// ---------------------------------------------------------------------------
// Block 1 MD-LSTM via MFMA: C=10, Cin=6, H=32, W=127. Block per (dir,b),
// 1024 thr. Whole x1-slice staged to LDS once (97.5KB); loop touches only
// LDS. 8 MFMA waves (2 m-tiles x 4 n-tiles), 3 mfma each (hi/lo split).
// ---------------------------------------------------------------------------
__global__ __launch_bounds__(1024, 1) void k_mdlstm1(
    const float* __restrict__ x1, const float* __restrict__ Wx,
    const float* __restrict__ Wh, const float* __restrict__ Wv,
    const float* __restrict__ bias, float* __restrict__ h1)
{
    const int dir = blockIdx.x >> 4, b = blockIdx.x & 15;
    const bool fH = dir >= 2, fW = (dir & 1) != 0;
    const int tid = threadIdx.x;
    const int wave = tid >> 6, lane = tid & 63;

    __shared__ float Xs1[32 * 127 * 6];           // 97.5 KB
    __shared__ __align__(16) ushort_t Ah[2][32][40];
    __shared__ __align__(16) ushort_t Al[2][32][40];
    __shared__ float P[32][68];
    __shared__ float cbuf[2][33][12];             // row 0 = permanent zeros

    for (int i = tid; i < 2 * 32 * 40; i += 1024) { ((ushort_t*)Ah)[i] = 0; ((ushort_t*)Al)[i] = 0; }
    for (int i = tid; i < 2 * 33 * 12; i += 1024) ((float*)cbuf)[i] = 0.f;
    for (int i = tid; i < 32 * 127 * 6; i += 1024)
        Xs1[i] = x1[(i / 6) * 96 + b * 6 + (i % 6)];
    __syncthreads();
    if (tid < 6) {                                // x for step 0 (cell 0 only)
        int rr = fH ? 31 : 0, cc = fW ? 126 : 0;
        float xv = Xs1[(rr * 127 + cc) * 6 + tid];
        ushort_t xh = f2bf(xv);
        Ah[0][0][20 + tid] = xh;
        Al[0][0][20 + tid] = f2bf(xv - bf2f(xh));
    }

    // B fragments in regs: wave w -> mt = w&1 (rows), nt = w>>1 (gate cols)
    const int mt = wave & 1, nt = wave >> 1;
    short8 bh = {0,0,0,0,0,0,0,0}, bl = {0,0,0,0,0,0,0,0};
    if (wave < 8) {
        int n = nt * 16 + (lane & 15);
#pragma unroll
        for (int jj = 0; jj < 8; jj++) {
            int k = (lane >> 4) * 8 + jj;
            float v = 0.f;
            if (n < 50) {
                if (k < 10)      v = Wh[(dir * 10 + k) * 50 + n];
                else if (k < 20) v = Wv[(dir * 10 + (k - 10)) * 50 + n];
                else if (k < 26) v = Wx[(dir * 6 + (k - 20)) * 50 + n];
            }
            ushort_t hi = f2bf(v);
            bh[jj] = (short)hi;
            bl[jj] = (short)f2bf(v - bf2f(hi));
        }
    }

    const int cell = tid / 10, u = tid % 10;      // gate mapping (tid<320)
    float br[5];
#pragma unroll
    for (int g = 0; g < 5; g++) br[g] = (tid < 320) ? bias[dir * 50 + g * 10 + u] : 0.f;
    const int ri = fH ? 31 - cell : cell;
    float creg = 0.f;
    __syncthreads();

    int p = 0;
    for (int d = 0; d < 158; d++) {
        // ---- MFMA phase (waves 0-7) ----
        if (wave < 8) {
            const int arow = mt * 16 + (lane & 15);
            const int koff = (lane >> 4) * 8;
            short8 ah = *(const short8*)&Ah[p][arow][koff];
            short8 al = *(const short8*)&Al[p][arow][koff];
            float4_t acc = {0.f, 0.f, 0.f, 0.f};
            acc = __builtin_amdgcn_mfma_f32_16x16x32_bf16(ah, bh, acc, 0, 0, 0);
            acc = __builtin_amdgcn_mfma_f32_16x16x32_bf16(al, bh, acc, 0, 0, 0);
            acc = __builtin_amdgcn_mfma_f32_16x16x32_bf16(ah, bl, acc, 0, 0, 0);
            int col = nt * 16 + (lane & 15);
            int r0 = (lane >> 4) * 4;
#pragma unroll
            for (int r = 0; r < 4; r++) P[mt * 16 + r0 + r][col] = acc[r];
        } else if (tid >= 512 && tid < 704) {
            // ---- x-staging for step d+1 from LDS slice (overlaps MFMA) ----
            int s = tid - 512, xc = s / 6, ci = s % 6;
            int jn = d + 1 - xc;
            if (jn >= 0 && jn < 127) {
                int rr = fH ? 31 - xc : xc, cc = fW ? 126 - jn : jn;
                float xv = Xs1[(rr * 127 + cc) * 6 + ci];
                ushort_t xh = f2bf(xv);
                Ah[1 - p][xc][20 + ci] = xh;
                Al[1 - p][xc][20 + ci] = f2bf(xv - bf2f(xh));
            }
        }
        __syncthreads();

        // ---- gate phase (tid<320) ----
        if (tid < 320) {
            int j = d - cell;
            if (j >= 0 && j < 127) {
                float ai  = P[cell][u]      + br[0];
                float af1 = P[cell][10 + u] + br[1];
                float af2 = P[cell][20 + u] + br[2];
                float ao  = P[cell][30 + u] + br[3];
                float ag  = P[cell][40 + u] + br[4];
                float cu = cbuf[p][cell][u];
                float cn = fsig(ai) * ftanh(ag) + fsig(af1) * creg + fsig(af2) * cu;
                float hn = fsig(ao) * ftanh(cn);
                creg = cn;
                cbuf[1 - p][cell + 1][u] = cn;
                ushort_t hh = f2bf(hn);
                float hhf = bf2f(hh);
                ushort_t hlo = f2bf(hn - hhf);
                Ah[1 - p][cell][u] = hh;          // hl slot for next step
                Al[1 - p][cell][u] = hlo;
                if (cell < 31) { Ah[1 - p][cell + 1][10 + u] = hh; Al[1 - p][cell + 1][10 + u] = hlo; }
                int cj = fW ? 126 - j : j;
                h1[(((dir * 16 + b) * 32 + ri) * 127 + cj) * 10 + u] = hn;
            }
        }
        __syncthreads();
        p ^= 1;
    }
}

// ---------------------------------------------------------------------------
// conv1: h1 (sum 4 dirs) [B,10,32,127] -> conv(20,10,2,4) s2 + tanh -> x2[16][62][16][20]
// ---------------------------------------------------------------------------
__global__ __launch_bounds__(320, 1) void k_conv1(
    const float* __restrict__ h1, const float* __restrict__ cw,
    const float* __restrict__ cb, float* __restrict__ x2)
{
    int blk = blockIdx.x;                 // 16*62
    int oh = blk / 62, ow = blk % 62;
    int t = threadIdx.x;
    int b = t / 20, co = t % 20;
    float w[10][2][4];
#pragma unroll
    for (int ci = 0; ci < 10; ci++)
#pragma unroll
        for (int kh = 0; kh < 2; kh++)
#pragma unroll
            for (int kw = 0; kw < 4; kw++)
                w[ci][kh][kw] = cw[((co * 10 + ci) * 2 + kh) * 4 + kw];
    float acc = cb[co];
    for (int dirb = 0; dirb < 4; dirb++) {
#pragma unroll
        for (int kh = 0; kh < 2; kh++) {
#pragma unroll
            for (int kw = 0; kw < 4; kw++) {
                const float* ptr = h1 + ((((dirb * 16 + b) * 32) + (2 * oh + kh)) * 127 + (2 * ow + kw)) * 10;
#pragma unroll
                for (int ci = 0; ci < 10; ci++)
                    acc = fmaf(ptr[ci], w[ci][kh][kw], acc);
            }
        }
    }
    x2[((oh * 62 + ow) * 16 + b) * 20 + co] = ftanh(acc);
}

// ---------------------------------------------------------------------------
// prep B for block2 MFMA, SPLIT hi/lo bf16:
// Bh/Bl[dir][k<128][n<256] = [Wh(50); Wv(50); Wx(20); 0pad]
// ---------------------------------------------------------------------------
__global__ __launch_bounds__(256) void k_prepB2(
    const float* __restrict__ Wh, const float* __restrict__ Wv,
    const float* __restrict__ Wx, ushort_t* __restrict__ Bh,
    ushort_t* __restrict__ Bl)
{
    int idx = blockIdx.x * 256 + threadIdx.x;      // 4*128*256 = 131072
    if (idx >= 131072) return;
    int dir = idx >> 15; int k = (idx >> 8) & 127; int n = idx & 255;
    float v = 0.f;
    if (n < 250) {
        if (k < 50)       v = Wh[(dir * 50 + k) * 250 + n];
        else if (k < 100) v = Wv[(dir * 50 + (k - 50)) * 250 + n];
        else if (k < 120) v = Wx[(dir * 20 + (k - 100)) * 250 + n];
    }
    ushort_t hi = f2bf(v);
    Bh[idx] = hi;
    Bl[idx] = f2bf(v - bf2f(hi));
}

// ---------------------------------------------------------------------------
// Block 2 MD-LSTM: C=50, Cin=20, H=16, W=62. Block per (dir,b), 1024 thr.
// Whole x2-slice staged to LDS once (79.4KB); loop touches only LDS.
// MFMA 16x16x32 bf16, A and B hi/lo: P = AhBh + AlBh + AhBl (12 mfma/wave).
// ---------------------------------------------------------------------------
__global__ __launch_bounds__(1024, 1) void k_mdlstm2(
    const float* __restrict__ x2, const ushort_t* __restrict__ BmH,
    const ushort_t* __restrict__ BmL,
    const float* __restrict__ bias, float* __restrict__ h2)
{
    const int dir = blockIdx.x >> 4, b = blockIdx.x & 15;
    const bool fH = dir >= 2, fW = (dir & 1) != 0;
    const int tid = threadIdx.x;
    const int wave = tid >> 6, lane = tid & 63;

    __shared__ float Xs2[16 * 62 * 20];           // 79.4 KB
    __shared__ __align__(16) ushort_t Ah[2][16][136];
    __shared__ __align__(16) ushort_t Al[2][16][136];
    __shared__ float P[16][260];
    __shared__ float cbuf[2][16][52];

    for (int i = tid; i < 2 * 16 * 136; i += 1024) { ((ushort_t*)Ah)[i] = 0; ((ushort_t*)Al)[i] = 0; }
    for (int i = tid; i < 16 * 62 * 20; i += 1024)
        Xs2[i] = x2[(i / 20) * 320 + b * 20 + (i % 20)];
    __syncthreads();
    if (tid < 20) {                                   // x for step 0 (cell 0 only)
        int ci = tid;
        int rr = fH ? 15 : 0, cc = fW ? 61 : 0;
        float xv = Xs2[(rr * 62 + cc) * 20 + ci];
        ushort_t xh = f2bf(xv);
        Ah[0][0][100 + ci] = xh;
        Al[0][0][100 + ci] = f2bf(xv - bf2f(xh));
    }

    short8 bfragH[4], bfragL[4];
    {
        const int n = wave * 16 + (lane & 15);
#pragma unroll
        for (int q = 0; q < 4; q++) {
#pragma unroll
            for (int jj = 0; jj < 8; jj++) {
                int k = q * 32 + (lane >> 4) * 8 + jj;
                bfragH[q][jj] = (short)BmH[(dir * 128 + k) * 256 + n];
                bfragL[q][jj] = (short)BmL[(dir * 128 + k) * 256 + n];
            }
        }
    }

    const int cell = tid / 50, u = tid % 50;          // gate mapping (tid<800)
    float bi = 0, bf1 = 0, bf2v = 0, bo = 0, bg = 0;
    if (tid < 800) {
        bi   = bias[dir * 250 + u];
        bf1  = bias[dir * 250 + 50 + u];
        bf2v = bias[dir * 250 + 100 + u];
        bo   = bias[dir * 250 + 150 + u];
        bg   = bias[dir * 250 + 200 + u];
    }
    const int rr_c = fH ? 15 - cell : cell;
    float creg = 0.f;
    __syncthreads();

    int p = 0;
    for (int d = 0; d < 77; d++) {
        // ---- MFMA phase ----
        {
            const int arow = lane & 15;
            const int koff = (lane >> 4) * 8;
            short8 ah[4], al[4];
#pragma unroll
            for (int q = 0; q < 4; q++) {
                ah[q] = *(const short8*)&Ah[p][arow][q * 32 + koff];
                al[q] = *(const short8*)&Al[p][arow][q * 32 + koff];
            }
            float4_t acc = {0.f, 0.f, 0.f, 0.f};
#pragma unroll
            for (int q = 0; q < 4; q++) acc = __builtin_amdgcn_mfma_f32_16x16x32_bf16(ah[q], bfragH[q], acc, 0, 0, 0);
#pragma unroll
            for (int q = 0; q < 4; q++) acc = __builtin_amdgcn_mfma_f32_16x16x32_bf16(al[q], bfragH[q], acc, 0, 0, 0);
#pragma unroll
            for (int q = 0; q < 4; q++) acc = __builtin_amdgcn_mfma_f32_16x16x32_bf16(ah[q], bfragL[q], acc, 0, 0, 0);
            int col = wave * 16 + (lane & 15);
            int r0 = (lane >> 4) * 4;
#pragma unroll
            for (int r = 0; r < 4; r++) P[r0 + r][col] = acc[r];
        }
        __syncthreads();

        // ---- gate phase (tid<800) ----
        if (tid < 800) {
            int j = d - cell;
            if (j >= 0 && j < 62) {
                float ai  = P[cell][u] + bi;
                float af1 = P[cell][50 + u] + bf1;
                float af2 = P[cell][100 + u] + bf2v;
                float ao  = P[cell][150 + u] + bo;
                float ag  = P[cell][200 + u] + bg;
                float cu = (cell == 0) ? 0.f : cbuf[p][cell - 1][u];
                float cn = fsig(ai) * ftanh(ag) + fsig(af1) * creg + fsig(af2) * cu;
                float hn = fsig(ao) * ftanh(cn);
                creg = cn;
                cbuf[1 - p][cell][u] = cn;
                ushort_t hh = f2bf(hn);
                float hhf = bf2f(hh);
                ushort_t hlo = f2bf(hn - hhf);
                Ah[1 - p][cell][u] = hh;
                Al[1 - p][cell][u] = hlo;
                if (cell < 15) { Ah[1 - p][cell + 1][50 + u] = hh; Al[1 - p][cell + 1][50 + u] = hlo; }
                int cc = fW ? 61 - j : j;
                h2[(((dir * 16 + b) * 16 + rr_c) * 62 + cc) * 50 + u] = hn;
            }
        } else if (tid >= 832 && tid < 992) {
            // ---- x-staging for step d+1 from LDS slice ----
            int s = tid - 832;
#pragma unroll
            for (int it = 0; it < 2; it++) {
                int item = s + it * 160;
                int xc = item / 20, ci = item % 20;
                int jn = d + 1 - xc;
                if (jn >= 0 && jn < 62) {
                    int rr = fH ? 15 - xc : xc, cc = fW ? 61 - jn : jn;
                    float xv = Xs2[(rr * 62 + cc) * 20 + ci];
                    ushort_t xh = f2bf(xv);
                    Ah[1 - p][xc][100 + ci] = xh;
                    Al[1 - p][xc][100 + ci] = f2bf(xv - bf2f(xh));
                }
            }
        }
        __syncthreads();
        p ^= 1;
    }
}

// ---------------------------------------------------------------------------
// final: out[b][r][c][n] = sum_{dir,cc} h2[dir][b][r][c][cc]*dW[dir][cc][n] + sum_dir db[dir][n]
// ---------------------------------------------------------------------------
__global__ __launch_bounds__(256) void k_final(
    const float* __restrict__ h2, const float* __restrict__ dW,
    const float* __restrict__ db, float* __restrict__ out)
{
    int blk = blockIdx.x;                  // 16*62
    int r = blk / 62, c = blk % 62;
    int t = threadIdx.x;
    __shared__ float hb[3200];             // [4][16][50]
    for (int i = t; i < 3200; i += 256) {
        int dirb = i / 800, rem = i % 800, b = rem / 50, u = rem % 50;
        hb[i] = h2[(((dirb * 16 + b) * 16 + r) * 62 + c) * 50 + u];
    }
    __syncthreads();
    for (int o = t; o < 1600; o += 256) {
        int b = o / 100, n = o % 100;
        float acc = db[n] + db[100 + n] + db[200 + n] + db[300 + n];
#pragma unroll
        for (int dirb = 0; dirb < 4; dirb++) {
            const float* hp = hb + (dirb * 16 + b) * 50;
            const float* wp = dW + dirb * 5000 + n;
#pragma unroll 10
            for (int cc2 = 0; cc2 < 50; cc2++)
                acc = fmaf(hp[cc2], wp[cc2 * 100], acc);
        }
        out[((b * 16 + r) * 62 + c) * 100 + n] = acc;
    }
}

// ---------------------------------------------------------------------------
extern "C" void kernel_launch(void* const* d_in, const int* in_sizes, int n_in,
                              void* d_out, int out_size, void* d_ws, size_t ws_size,
                              hipStream_t stream)
{
    const float* x     = (const float*)d_in[0];
    const float* p0_Wx = (const float*)d_in[1];
    const float* p0_Wh = (const float*)d_in[2];
    const float* p0_Wv = (const float*)d_in[3];
    const float* p0_b  = (const float*)d_in[4];
    const float* c0_w  = (const float*)d_in[5];
    const float* c0_b  = (const float*)d_in[6];
    const float* p1_Wx = (const float*)d_in[7];
    const float* p1_Wh = (const float*)d_in[8];
    const float* p1_Wv = (const float*)d_in[9];
    const float* p1_b  = (const float*)d_in[10];
    const float* c1_w  = (const float*)d_in[11];
    const float* c1_b  = (const float*)d_in[12];
    const float* p2_Wx = (const float*)d_in[13];
    const float* p2_Wh = (const float*)d_in[14];
    const float* p2_Wv = (const float*)d_in[15];
    const float* p2_b  = (const float*)d_in[16];
    const float* dW    = (const float*)d_in[17];
    const float* db    = (const float*)d_in[18];
    float* out = (float*)d_out;
    float* ws  = (float*)d_ws;

    float* h0 = ws;                        // 4*16*64*256*2  = 2,097,152 fl
    float* x1 = h0 + 2097152;              // 32*127*16*6    =   390,144 fl
    float* h1 = x1 + 390144;               // 4*16*32*127*10 = 2,600,960 fl
    float* x2 = h1 + 2600960;              // 16*62*16*20    =   317,440 fl
    float* h2 = x2 + 317440;               // 4*16*16*62*50  = 3,174,400 fl
    ushort_t* BmH = (ushort_t*)(h2 + 3174400); // 4*128*256 bf16
    ushort_t* BmL = BmH + 131072;              // 4*128*256 bf16

    k_prepB2<<<512, 256, 0, stream>>>(p2_Wh, p2_Wv, p2_Wx, BmH, BmL);
    k_mdlstm0<<<64, 64, 0, stream>>>(x, p0_Wx, p0_Wh, p0_Wv, p0_b, h0);
    k_conv0<<<32 * 127, 128, 0, stream>>>(h0, c0_w, c0_b, x1);
    k_mdlstm1<<<64, 1024, 0, stream>>>(x1, p1_Wx, p1_Wh, p1_Wv, p1_b, h1);
    k_conv1<<<16 * 62, 320, 0, stream>>>(h1, c1_w, c1_b, x2);
    k_mdlstm2<<<64, 1024, 0, stream>>>(x2, BmH, BmL, p2_b, h2);
    k_final<<<16 * 62, 256, 0, stream>>>(h2, dW, db, out);
}